// Round 1
// baseline (206.358 us; speedup 1.0000x reference)
//
#include <hip/hip_runtime.h>
#include <hip/hip_bf16.h>
#include <math.h>

#define BATCH 16384
#define NF 26
#define ND 13
#define VOC 100000
#define EDIM 16
#define KP0 448
#define KP1 416

typedef __bf16 bf16x8 __attribute__((ext_vector_type(8)));
typedef float f32x4 __attribute__((ext_vector_type(4)));
using bf16 = __hip_bfloat16;

// ---------- weight transpose + cast:  Wt[n][k] = W[k][n] (bf16, zero-pad k>=K)
__global__ void transpose_w_kernel(const float* __restrict__ W, bf16* __restrict__ Wt,
                                   int K, int KP) {
  int idx = blockIdx.x * 256 + threadIdx.x;
  if (idx >= 400 * KP) return;
  int k = idx % KP;
  int n = idx / KP;
  float v = (k < K) ? W[(size_t)k * 400 + n] : 0.f;
  Wt[idx] = __float2bfloat16(v);
}

// ---------- gather + FM terms. One wave per sample.
__global__ __launch_bounds__(256) void gather_fm_kernel(
    const int* __restrict__ xs, const float* __restrict__ xd,
    const float* __restrict__ emb1, const float* __restrict__ emb2,
    const float* __restrict__ wd, const float* __restrict__ bias,
    bf16* __restrict__ h0, float* __restrict__ partial) {
  int gid = blockIdx.x * blockDim.x + threadIdx.x;
  int b = gid >> 6;
  int lane = threadIdx.x & 63;
  int fsub = lane >> 4;      // 0..3
  int e = lane & 15;         // 0..15
  float s_acc = 0.f, sq_acc = 0.f, lin = 0.f;
#pragma unroll
  for (int it = 0; it < 7; ++it) {
    int f = it * 4 + fsub;
    if (f < NF) {
      int idx = xs[b * NF + f];
      float v = emb2[((size_t)(f * VOC + idx)) * EDIM + e];
      h0[(size_t)b * KP0 + f * EDIM + e] = __float2bfloat16(v);
      s_acc += v;
      sq_acc += v * v;
      if (e == 0) lin += emb1[(size_t)f * VOC + idx];
    }
  }
  // dense part: cols 416..447 (13 real + zero pad)
  if (lane < 32) {
    float v = 0.f;
    if (lane < ND) { v = xd[b * ND + lane]; lin += v * wd[lane]; }
    h0[(size_t)b * KP0 + 416 + lane] = __float2bfloat16(v);
  }
  // s_e = sum over features (reduce across the 4 fsub groups)
  float s_tot = s_acc;
  s_tot += __shfl_xor(s_tot, 16);
  s_tot += __shfl_xor(s_tot, 32);
  float r0 = s_tot * s_tot;   // each e duplicated 4x -> divide by 4 later
  float r1 = sq_acc;
  float r2 = lin;
#pragma unroll
  for (int off = 1; off < 64; off <<= 1) {
    r0 += __shfl_xor(r0, off);
    r1 += __shfl_xor(r1, off);
    r2 += __shfl_xor(r2, off);
  }
  if (lane == 0) {
    float cross = 0.5f * (r0 * 0.25f - r1);
    partial[b] = bias[0] + r2 + cross;
  }
}

// ---------- MFMA GEMM: C[64 x 400] per block; wave w owns rows w*16..w*16+15.
// A: [M][KP] bf16 row-major.  Wt: [400][KP] bf16 (transposed weights).
// !FINAL: out = relu(A@W + b) -> [M][416] bf16 (cols 400..415 zeroed).
// FINAL:  out[row] = sigmoid(partial[row] + relu(A@W + b) . fw)
template <int KP, bool FINAL>
__global__ __launch_bounds__(256) void mlp_kernel(
    const bf16* __restrict__ A, const bf16* __restrict__ Wt,
    const float* __restrict__ bias, bf16* __restrict__ outH,
    const float* __restrict__ fw, const float* __restrict__ partial,
    float* __restrict__ outF) {
  int blk = blockIdx.x, tid = threadIdx.x;
  int w = tid >> 6, lane = tid & 63;
  int r = lane & 15, g = lane >> 4;
  int row0 = blk * 64 + w * 16;

  const bf16x8* Ap =
      reinterpret_cast<const bf16x8*>(A + (size_t)(row0 + r) * KP + g * 8);

  f32x4 acc[25];
#pragma unroll
  for (int nt = 0; nt < 25; ++nt) acc[nt] = (f32x4){0.f, 0.f, 0.f, 0.f};

  for (int k = 0; k < KP / 32; ++k) {
    bf16x8 a = Ap[k * 4];
#pragma unroll
    for (int nt = 0; nt < 25; ++nt) {
      bf16x8 bfrag = *reinterpret_cast<const bf16x8*>(
          Wt + (size_t)(nt * 16 + r) * KP + k * 32 + g * 8);
      acc[nt] = __builtin_amdgcn_mfma_f32_16x16x32_bf16(a, bfrag, acc[nt], 0, 0, 0);
    }
  }

  if (!FINAL) {
#pragma unroll
    for (int nt = 0; nt < 25; ++nt) {
      int col = nt * 16 + r;
      float bv = bias[col];
#pragma unroll
      for (int q = 0; q < 4; ++q) {
        float v = fmaxf(acc[nt][q] + bv, 0.f);
        outH[(size_t)(row0 + g * 4 + q) * KP1 + col] = __float2bfloat16(v);
      }
    }
    // zero-pad cols 400..415 for this block's 64 rows
    for (int i = tid; i < 64 * 16; i += 256) {
      int rr = i >> 4, cc = 400 + (i & 15);
      outH[(size_t)(blk * 64 + rr) * KP1 + cc] = __float2bfloat16(0.f);
    }
  } else {
    float p0 = 0.f, p1 = 0.f, p2 = 0.f, p3 = 0.f;
#pragma unroll
    for (int nt = 0; nt < 25; ++nt) {
      int col = nt * 16 + r;
      float bv = bias[col];
      float fv = fw[col];
      p0 += fmaxf(acc[nt][0] + bv, 0.f) * fv;
      p1 += fmaxf(acc[nt][1] + bv, 0.f) * fv;
      p2 += fmaxf(acc[nt][2] + bv, 0.f) * fv;
      p3 += fmaxf(acc[nt][3] + bv, 0.f) * fv;
    }
#pragma unroll
    for (int off = 1; off < 16; off <<= 1) {
      p0 += __shfl_xor(p0, off);
      p1 += __shfl_xor(p1, off);
      p2 += __shfl_xor(p2, off);
      p3 += __shfl_xor(p3, off);
    }
    if (r < 4) {
      int row = row0 + g * 4 + r;
      float pv = (r == 0) ? p0 : (r == 1) ? p1 : (r == 2) ? p2 : p3;
      float x = partial[row] + pv;
      outF[row] = 1.f / (1.f + expf(-x));
    }
  }
}

extern "C" void kernel_launch(void* const* d_in, const int* in_sizes, int n_in,
                              void* d_out, int out_size, void* d_ws, size_t ws_size,
                              hipStream_t stream) {
  const int* xs = (const int*)d_in[0];
  const float* xd = (const float*)d_in[1];
  const float* emb1 = (const float*)d_in[2];
  const float* emb2 = (const float*)d_in[3];
  const float* wd = (const float*)d_in[4];
  const float* bias = (const float*)d_in[5];
  const float* w0 = (const float*)d_in[6];
  const float* b0 = (const float*)d_in[7];
  const float* w1 = (const float*)d_in[8];
  const float* b1 = (const float*)d_in[9];
  const float* w2 = (const float*)d_in[10];
  const float* b2 = (const float*)d_in[11];
  const float* fw = (const float*)d_in[12];
  float* out = (float*)d_out;

  char* ws = (char*)d_ws;
  float* partial = (float*)(ws + 0);            // 65536 B
  bf16* wt0 = (bf16*)(ws + 65536);              // 400*448*2 = 358400
  bf16* wt1 = (bf16*)(ws + 423936);             // 400*416*2 = 332800
  bf16* wt2 = (bf16*)(ws + 756736);             // 332800
  bf16* h0  = (bf16*)(ws + 1089536);            // 16384*448*2 = 14680064
  bf16* h1  = (bf16*)(ws + 15769600);           // 16384*416*2 = 13631488
  bf16* h2  = h0;                               // h0 dead after layer 0 -> reuse

  transpose_w_kernel<<<(400 * KP0 + 255) / 256, 256, 0, stream>>>(w0, wt0, 429, KP0);
  transpose_w_kernel<<<(400 * KP1 + 255) / 256, 256, 0, stream>>>(w1, wt1, 400, KP1);
  transpose_w_kernel<<<(400 * KP1 + 255) / 256, 256, 0, stream>>>(w2, wt2, 400, KP1);

  gather_fm_kernel<<<BATCH / 4, 256, 0, stream>>>(xs, xd, emb1, emb2, wd, bias, h0, partial);

  mlp_kernel<KP0, false><<<256, 256, 0, stream>>>(h0, wt0, b0, h1, nullptr, nullptr, nullptr);
  mlp_kernel<KP1, false><<<256, 256, 0, stream>>>(h1, wt1, b1, h2, nullptr, nullptr, nullptr);
  mlp_kernel<KP1, true><<<256, 256, 0, stream>>>(h2, wt2, b2, nullptr, fw, partial, out);
}

// Round 2
// 94.376 us; speedup vs baseline: 2.1866x; 2.1866x over previous
//
#include <hip/hip_runtime.h>
#include <hip/hip_bf16.h>
#include <math.h>

#define BATCH 16384
#define NF 26
#define ND 13
#define VOC 100000
#define EDIM 16
#define KP0 448
#define KP1 416
#define NWT 480  // padded row count of transposed weight buffers

typedef __bf16 bf16x8 __attribute__((ext_vector_type(8)));
typedef float f32x4 __attribute__((ext_vector_type(4)));
using bf16 = __hip_bfloat16;

__device__ __forceinline__ void gload_lds16(const void* g, void* l) {
  __builtin_amdgcn_global_load_lds(
      (const __attribute__((address_space(1))) void*)g,
      (__attribute__((address_space(3))) void*)l, 16, 0, 0);
}

// ---------- weight transpose + cast: Wt[n][k] = W[k][n], zero-pad n>=400, k>=K
__global__ void transpose_w_kernel(const float* __restrict__ W, bf16* __restrict__ Wt,
                                   int K, int KP) {
  int idx = blockIdx.x * 256 + threadIdx.x;
  if (idx >= NWT * KP) return;
  int k = idx % KP;
  int n = idx / KP;
  float v = (k < K && n < 400) ? W[(size_t)k * 400 + n] : 0.f;
  Wt[idx] = __float2bfloat16(v);
}

// ---------- gather + FM terms. One wave per sample.
__global__ __launch_bounds__(256) void gather_fm_kernel(
    const int* __restrict__ xs, const float* __restrict__ xd,
    const float* __restrict__ emb1, const float* __restrict__ emb2,
    const float* __restrict__ wd, const float* __restrict__ bias,
    bf16* __restrict__ h0, float* __restrict__ partial) {
  int gid = blockIdx.x * blockDim.x + threadIdx.x;
  int b = gid >> 6;
  int lane = threadIdx.x & 63;
  int fsub = lane >> 4;      // 0..3
  int e = lane & 15;         // 0..15
  float s_acc = 0.f, sq_acc = 0.f, lin = 0.f;
#pragma unroll
  for (int it = 0; it < 7; ++it) {
    int f = it * 4 + fsub;
    if (f < NF) {
      int idx = xs[b * NF + f];
      float v = emb2[((size_t)(f * VOC + idx)) * EDIM + e];
      h0[(size_t)b * KP0 + f * EDIM + e] = __float2bfloat16(v);
      s_acc += v;
      sq_acc += v * v;
      if (e == 0) lin += emb1[(size_t)f * VOC + idx];
    }
  }
  // dense part: cols 416..447 (13 real + zero pad)
  if (lane < 32) {
    float v = 0.f;
    if (lane < ND) { v = xd[b * ND + lane]; lin += v * wd[lane]; }
    h0[(size_t)b * KP0 + 416 + lane] = __float2bfloat16(v);
  }
  float s_tot = s_acc;
  s_tot += __shfl_xor(s_tot, 16);
  s_tot += __shfl_xor(s_tot, 32);
  float r0 = s_tot * s_tot;   // each e duplicated 4x -> /4 later
  float r1 = sq_acc;
  float r2 = lin;
#pragma unroll
  for (int off = 1; off < 64; off <<= 1) {
    r0 += __shfl_xor(r0, off);
    r1 += __shfl_xor(r1, off);
    r2 += __shfl_xor(r2, off);
  }
  if (lane == 0) {
    float cross = 0.5f * (r0 * 0.25f - r1);
    partial[b] = bias[0] + r2 + cross;
  }
}

// ---------- MFMA GEMM, LDS double-buffered B.
// Block: 128 rows x 208 cols (col-half ch). 4 waves x 32 rows (2 row-tiles).
// B k-slab staged in LDS: 256 rows x 32 k bf16 = 16 KB, double-buffered.
// !FINAL: outH = relu(A@W + b) as [BATCH][416] bf16 (cols>=400 zeroed).
// FINAL:  dotb[ch*BATCH + row] = sum_cols relu(.)*fw  (partials per col-half)
template <int KP, bool FINAL>
__global__ __launch_bounds__(256) void mlp2_kernel(
    const bf16* __restrict__ A, const bf16* __restrict__ Wt,
    const float* __restrict__ bias, bf16* __restrict__ outH,
    const float* __restrict__ fw, float* __restrict__ dotb) {
  constexpr int NK = KP / 32;
  __shared__ __align__(16) bf16 slab[2][256 * 32];
  const int blk = blockIdx.x;
  const int ch = blk & 1, blkRow = blk >> 1;
  const int tid = threadIdx.x, w = tid >> 6, lane = tid & 63;
  const int r = lane & 15, g = lane >> 4;
  const int row0 = blkRow * 128 + w * 32;
  const int ncol0 = ch * 208;

  const char* wslab = (const char*)(Wt + (size_t)ncol0 * KP);

  f32x4 acc[2][13];
#pragma unroll
  for (int i = 0; i < 2; ++i)
#pragma unroll
    for (int nt = 0; nt < 13; ++nt) acc[i][nt] = (f32x4){0.f, 0.f, 0.f, 0.f};

  // stage k-slab k into LDS buffer buf (4 rounds x 1 chunk/thread, 16 B each)
  auto stage = [&](int buf, int k) {
#pragma unroll
    for (int rd = 0; rd < 4; ++rd) {
      int c0 = rd * 256 + w * 64;          // wave-uniform chunk base
      int c = c0 + lane;                   // per-lane chunk
      int rw = c >> 2, ko = (c & 3) * 16;  // row in slab, 16B piece of 64B row
      gload_lds16(wslab + (size_t)rw * (KP * 2) + k * 64 + ko,
                  (char*)&slab[buf][0] + (size_t)c0 * 16);
    }
  };

  stage(0, 0);
  __syncthreads();

  const char* Ab0 = (const char*)(A + (size_t)(row0 + r) * KP);
  const char* Ab1 = (const char*)(A + (size_t)(row0 + 16 + r) * KP);

  for (int k = 0; k < NK; ++k) {
    const int cur = k & 1;
    if (k + 1 < NK) stage(cur ^ 1, k + 1);
    bf16x8 a0 = *(const bf16x8*)(Ab0 + k * 64 + g * 16);
    bf16x8 a1 = *(const bf16x8*)(Ab1 + k * 64 + g * 16);
    const char* sb = (const char*)&slab[cur][0] + r * 64 + g * 16;
#pragma unroll
    for (int nt = 0; nt < 13; ++nt) {
      bf16x8 b = *(const bf16x8*)(sb + nt * 1024);
      acc[0][nt] = __builtin_amdgcn_mfma_f32_16x16x32_bf16(a0, b, acc[0][nt], 0, 0, 0);
      acc[1][nt] = __builtin_amdgcn_mfma_f32_16x16x32_bf16(a1, b, acc[1][nt], 0, 0, 0);
    }
    __syncthreads();
  }

  if (!FINAL) {
#pragma unroll
    for (int rt = 0; rt < 2; ++rt)
#pragma unroll
      for (int nt = 0; nt < 13; ++nt) {
        int col = ncol0 + nt * 16 + r;
        bool live = (col < 400);
        float bv = live ? bias[col] : 0.f;
#pragma unroll
        for (int q = 0; q < 4; ++q) {
          float v = live ? fmaxf(acc[rt][nt][q] + bv, 0.f) : 0.f;
          outH[(size_t)(row0 + rt * 16 + g * 4 + q) * KP1 + col] = __float2bfloat16(v);
        }
      }
  } else {
    float pr[2][4] = {{0.f, 0.f, 0.f, 0.f}, {0.f, 0.f, 0.f, 0.f}};
#pragma unroll
    for (int rt = 0; rt < 2; ++rt)
#pragma unroll
      for (int nt = 0; nt < 13; ++nt) {
        int col = ncol0 + nt * 16 + r;
        if (col < 400) {
          float bv = bias[col], fv = fw[col];
#pragma unroll
          for (int q = 0; q < 4; ++q)
            pr[rt][q] += fmaxf(acc[rt][nt][q] + bv, 0.f) * fv;
        }
      }
#pragma unroll
    for (int rt = 0; rt < 2; ++rt)
#pragma unroll
      for (int q = 0; q < 4; ++q)
#pragma unroll
        for (int off = 1; off < 16; off <<= 1)
          pr[rt][q] += __shfl_xor(pr[rt][q], off);
    if (r < 4) {
#pragma unroll
      for (int rt = 0; rt < 2; ++rt) {
        float v = (r == 0) ? pr[rt][0] : (r == 1) ? pr[rt][1]
                : (r == 2) ? pr[rt][2] : pr[rt][3];
        dotb[(size_t)ch * BATCH + row0 + rt * 16 + g * 4 + r] = v;
      }
    }
  }
}

// ---------- combine partials + sigmoid
__global__ void finish_kernel(const float* __restrict__ partial,
                              const float* __restrict__ dotb,
                              float* __restrict__ out) {
  int i = blockIdx.x * 256 + threadIdx.x;
  if (i < BATCH) {
    float x = partial[i] + dotb[i] + dotb[i + BATCH];
    out[i] = 1.f / (1.f + expf(-x));
  }
}

extern "C" void kernel_launch(void* const* d_in, const int* in_sizes, int n_in,
                              void* d_out, int out_size, void* d_ws, size_t ws_size,
                              hipStream_t stream) {
  const int* xs = (const int*)d_in[0];
  const float* xd = (const float*)d_in[1];
  const float* emb1 = (const float*)d_in[2];
  const float* emb2 = (const float*)d_in[3];
  const float* wd = (const float*)d_in[4];
  const float* bias = (const float*)d_in[5];
  const float* w0 = (const float*)d_in[6];
  const float* b0 = (const float*)d_in[7];
  const float* w1 = (const float*)d_in[8];
  const float* b1 = (const float*)d_in[9];
  const float* w2 = (const float*)d_in[10];
  const float* b2 = (const float*)d_in[11];
  const float* fw = (const float*)d_in[12];
  float* out = (float*)d_out;

  char* ws = (char*)d_ws;
  float* partial = (float*)(ws + 0);              //  65536 B
  float* dotb    = (float*)(ws + 65536);          // 131072 B (2 x 16384 f32)
  bf16* wt0 = (bf16*)(ws + 196608);               // 480*448*2 = 430080
  bf16* wt1 = (bf16*)(ws + 626688);               // 480*416*2 = 399360
  bf16* wt2 = (bf16*)(ws + 1026048);              // 399360
  bf16* h0  = (bf16*)(ws + 1425408);              // 16384*448*2 = 14680064
  bf16* h1  = (bf16*)(ws + 16105472);             // 16384*416*2 = 13631488
  bf16* h2  = h0;                                 // h0 dead after layer 0

  transpose_w_kernel<<<(NWT * KP0 + 255) / 256, 256, 0, stream>>>(w0, wt0, 429, KP0);
  transpose_w_kernel<<<(NWT * KP1 + 255) / 256, 256, 0, stream>>>(w1, wt1, 400, KP1);
  transpose_w_kernel<<<(NWT * KP1 + 255) / 256, 256, 0, stream>>>(w2, wt2, 400, KP1);

  gather_fm_kernel<<<BATCH / 4, 256, 0, stream>>>(xs, xd, emb1, emb2, wd, bias, h0, partial);

  mlp2_kernel<KP0, false><<<256, 256, 0, stream>>>(h0, wt0, b0, h1, nullptr, nullptr);
  mlp2_kernel<KP1, false><<<256, 256, 0, stream>>>(h1, wt1, b1, h2, nullptr, nullptr);
  mlp2_kernel<KP1, true><<<256, 256, 0, stream>>>(h2, wt2, b2, nullptr, fw, dotb);

  finish_kernel<<<BATCH / 256, 256, 0, stream>>>(partial, dotb, out);
}